// Round 2
// baseline (659.581 us; speedup 1.0000x reference)
//
#include <hip/hip_runtime.h>
#include <cstdint>
#include <cstddef>

typedef __bf16 bf16x8v __attribute__((ext_vector_type(8)));
typedef float f32x4v __attribute__((ext_vector_type(4)));

// async global->LDS, 16B per lane; LDS dest is wave-uniform base (HW adds lane*16)
__device__ __forceinline__ void gload_lds16(const void* g, void* l) {
  __builtin_amdgcn_global_load_lds((const __attribute__((address_space(1))) void*)g,
                                   (__attribute__((address_space(3))) void*)l,
                                   16, 0, 0);
}

__device__ __forceinline__ bf16x8v cvt_bf16x8(f32x4v a, f32x4v b) {
  bf16x8v r;
  r[0] = (__bf16)a[0]; r[1] = (__bf16)a[1]; r[2] = (__bf16)a[2]; r[3] = (__bf16)a[3];
  r[4] = (__bf16)b[0]; r[5] = (__bf16)b[1]; r[6] = (__bf16)b[2]; r[7] = (__bf16)b[3];
  return r;
}

// ---------------- params: linearize the Toeplitz generator (2047 fp32) ----------------
__global__ __launch_bounds__(256) void params_kernel(const float* __restrict__ W1,
                                                     float* __restrict__ params) {
  int p = blockIdx.x * 256 + threadIdx.x;
  if (p < 2047)
    params[p] = (p < 1024) ? W1[(size_t)(1023 - p) << 10] : W1[p - 1023];
}

// ---------------- pack: Acat bf16 [65536,1024], toep bf16 [1024,1024], Wcat [128,1024]
// unit = 8 consecutive bf16 outputs. All reads coalesced (params is L2-resident).
__global__ __launch_bounds__(256) void pack_kernel(const float* __restrict__ x,
                                                   const float* __restrict__ h,
                                                   const float* __restrict__ params,
                                                   const float* __restrict__ Ws,
                                                   const float* __restrict__ Wi,
                                                   __bf16* __restrict__ Acat,
                                                   __bf16* __restrict__ toep,
                                                   __bf16* __restrict__ Wcat) {
  long u = (long)blockIdx.x * 256 + threadIdx.x;
  if (u < 8388608L) {                       // Acat: 65536*1024/8 units
    int r = (int)(u >> 7), cg = (int)(u & 127);
    const float* s = (cg < 8) ? x + (size_t)r * 64 + cg * 8
                              : h + (size_t)r * 960 + (cg - 8) * 8;
    f32x4v a = *(const f32x4v*)s, b = *(const f32x4v*)(s + 4);
    *(bf16x8v*)(Acat + ((size_t)r << 10) + cg * 8) = cvt_bf16x8(a, b);
  } else if (u < 8519680L) {                // toep: 1024*1024/8 units
    long t = u - 8388608L;
    int i = (int)(t >> 7), j0 = (int)(t & 127) * 8;
    const float* s = params + (1023 - i + j0);   // unaligned -> scalar loads, L2-hit
    bf16x8v o;
#pragma unroll
    for (int e = 0; e < 8; ++e) o[e] = (__bf16)s[e];
    *(bf16x8v*)(toep + ((size_t)i << 10) + j0) = o;
  } else {                                  // Wcat: 128*1024/8 units
    long t = u - 8519680L;
    int n = (int)(t >> 7), k0 = (int)(t & 127) * 8;
    const float* s = (n < 64) ? Ws + ((size_t)n << 10) + k0
                              : Wi + ((size_t)(n - 64) << 10) + k0;
    f32x4v a = *(const f32x4v*)s, b = *(const f32x4v*)(s + 4);
    *(bf16x8v*)(Wcat + ((size_t)n << 10) + k0) = cvt_bf16x8(a, b);
  }
}

// ---------------- GEMM1 (bf16 A): q = relu(Acat @ toep^T + b1), bf16 out --------------
// 128x128 tile, BK=32, double-buffered global_load_lds on both operands
__global__ __launch_bounds__(256) void gemm1_dma(const __bf16* __restrict__ Acat,
                                                 const __bf16* __restrict__ toep,
                                                 const float* __restrict__ b1,
                                                 __bf16* __restrict__ q) {
  __shared__ __align__(16) __bf16 Ab[2][128 * 32];
  __shared__ __align__(16) __bf16 Bb[2][128 * 32];
  const int tid = threadIdx.x, wid = tid >> 6, lane = tid & 63;
  const int wrow = wid >> 1, wcol = wid & 1;
  const int m0 = (blockIdx.x >> 3) << 7;
  const int n0 = (blockIdx.x & 7) << 7;
  const int quad = lane >> 4, l15 = lane & 15;
  const int rl = lane >> 2, seg = lane & 3;   // DMA: 4 lanes/row, 16 rows/instr

  f32x4v acc[4][4] = {};

  auto stage = [&](int buf, int kt) {
    int k0 = kt << 5;
#pragma unroll
    for (int c = 0; c < 2; ++c) {
      int rb = wid * 32 + c * 16;
      gload_lds16(Acat + (((size_t)(m0 + rb + rl)) << 10) + k0 + seg * 8, &Ab[buf][rb * 32]);
      gload_lds16(toep + (((size_t)(n0 + rb + rl)) << 10) + k0 + seg * 8, &Bb[buf][rb * 32]);
    }
  };

  stage(0, 0);
  for (int kt = 0; kt < 32; ++kt) {
    int cur = kt & 1;
    __syncthreads();                         // drains vmcnt(0): DMA(cur) complete
    if (kt < 31) stage(cur ^ 1, kt + 1);     // next chunk flies during MFMA phase
    bf16x8v af[4], bfr[4];
#pragma unroll
    for (int r = 0; r < 4; ++r)
      af[r] = *(const bf16x8v*)&Ab[cur][(wrow * 64 + r * 16 + l15) * 32 + quad * 8];
#pragma unroll
    for (int c = 0; c < 4; ++c)
      bfr[c] = *(const bf16x8v*)&Bb[cur][(wcol * 64 + c * 16 + l15) * 32 + quad * 8];
#pragma unroll
    for (int r = 0; r < 4; ++r)
#pragma unroll
      for (int c = 0; c < 4; ++c)
        acc[r][c] = __builtin_amdgcn_mfma_f32_16x16x32_bf16(af[r], bfr[c], acc[r][c], 0, 0, 0);
  }

  // epilogue: C/D col=lane&15, row=quad*4+e (verified round 1)
#pragma unroll
  for (int c = 0; c < 4; ++c) {
    int col = n0 + wcol * 64 + c * 16 + l15;
    float bias = b1[col];
#pragma unroll
    for (int r = 0; r < 4; ++r)
#pragma unroll
      for (int e = 0; e < 4; ++e) {
        int row = m0 + wrow * 64 + r * 16 + quad * 4 + e;
        q[((size_t)row << 10) + col] = (__bf16)fmaxf(acc[r][c][e] + bias, 0.0f);
      }
  }
}

// ---------------- GEMM1 fallback (fp32 A fused) — round-1 passing version -------------
__global__ __launch_bounds__(256) void gemm1_fused(const float* __restrict__ x,
                                                   const float* __restrict__ h,
                                                   const __bf16* __restrict__ toep,
                                                   const float* __restrict__ b1,
                                                   __bf16* __restrict__ q) {
  __shared__ __align__(16) __bf16 At[128 * 32];
  __shared__ __align__(16) __bf16 Bt[128 * 32];
  const int tid = threadIdx.x, wid = tid >> 6, lane = tid & 63;
  const int wrow = wid >> 1, wcol = wid & 1;
  const int m0 = (blockIdx.x >> 3) << 7;
  const int n0 = (blockIdx.x & 7) << 7;
  const int quad = lane >> 4, l15 = lane & 15;
  const int rl = lane >> 2, seg = lane & 3;

  f32x4v acc[4][4] = {};
  auto a_ptr = [&](int k0, int t) -> const f32x4v* {
    const float* s; int ld, kk;
    if (k0 < 64) { s = x; ld = 64; kk = k0; } else { s = h; ld = 960; kk = k0 - 64; }
    int row = m0 + wid * 32 + t * 16 + rl;
    return (const f32x4v*)(s + (size_t)row * ld + kk + seg * 8);
  };
  f32x4v pv[2][2];
  { const f32x4v* p0 = a_ptr(0, 0); pv[0][0] = p0[0]; pv[0][1] = p0[1];
    const f32x4v* p1 = a_ptr(0, 1); pv[1][0] = p1[0]; pv[1][1] = p1[1]; }

  for (int k0 = 0; k0 < 1024; k0 += 32) {
    __syncthreads();
    { int rb = wid * 32;
#pragma unroll
      for (int c = 0; c < 2; ++c) {
        int row = rb + c * 16 + rl;
        gload_lds16(toep + (((size_t)(n0 + row)) << 10) + k0 + seg * 8, &Bt[(rb + c * 16) * 32]);
      } }
#pragma unroll
    for (int t = 0; t < 2; ++t) {
      int row = wid * 32 + t * 16 + rl;
      *(bf16x8v*)&At[row * 32 + seg * 8] = cvt_bf16x8(pv[t][0], pv[t][1]);
    }
    __syncthreads();
    if (k0 + 32 < 1024) {
      const f32x4v* p0 = a_ptr(k0 + 32, 0); f32x4v n00 = p0[0], n01 = p0[1];
      const f32x4v* p1 = a_ptr(k0 + 32, 1); f32x4v n10 = p1[0], n11 = p1[1];
      pv[0][0] = n00; pv[0][1] = n01; pv[1][0] = n10; pv[1][1] = n11;
    }
    bf16x8v af[4], bfr[4];
#pragma unroll
    for (int r = 0; r < 4; ++r)
      af[r] = *(const bf16x8v*)&At[(wrow * 64 + r * 16 + l15) * 32 + quad * 8];
#pragma unroll
    for (int c = 0; c < 4; ++c)
      bfr[c] = *(const bf16x8v*)&Bt[(wcol * 64 + c * 16 + l15) * 32 + quad * 8];
#pragma unroll
    for (int r = 0; r < 4; ++r)
#pragma unroll
      for (int c = 0; c < 4; ++c)
        acc[r][c] = __builtin_amdgcn_mfma_f32_16x16x32_bf16(af[r], bfr[c], acc[r][c], 0, 0, 0);
  }
#pragma unroll
  for (int c = 0; c < 4; ++c) {
    int col = n0 + wcol * 64 + c * 16 + l15;
    float bias = b1[col];
#pragma unroll
    for (int r = 0; r < 4; ++r)
#pragma unroll
      for (int e = 0; e < 4; ++e) {
        int row = m0 + wrow * 64 + r * 16 + quad * 4 + e;
        q[((size_t)row << 10) + col] = (__bf16)fmaxf(acc[r][c][e] + bias, 0.0f);
      }
  }
}

// ---------------- GEMM2: [slope|intercept] = act(q @ Wcat^T + bias) -------------------
// 64-row tiles (1024 blocks), BK=64, double-buffered DMA; wave tile 32x64
__global__ __launch_bounds__(256) void gemm2_dma(const __bf16* __restrict__ q,
                                                 const __bf16* __restrict__ Wcat,
                                                 const float* __restrict__ b_slope,
                                                 const float* __restrict__ b_int,
                                                 float* __restrict__ out) {
  __shared__ __align__(16) __bf16 Ab[2][64 * 64];
  __shared__ __align__(16) __bf16 Bb[2][128 * 64];
  const int tid = threadIdx.x, wid = tid >> 6, lane = tid & 63;
  const int wrow = wid >> 1, wcol = wid & 1;
  const int m0 = blockIdx.x << 6;
  const int quad = lane >> 4, l15 = lane & 15;
  const int r8 = lane >> 3, s8 = lane & 7;    // DMA: 8 lanes/row (128B rows), 8 rows/instr

  f32x4v acc[2][4] = {};

  auto stage = [&](int buf, int kt) {
    int k0 = kt << 6;
#pragma unroll
    for (int j = 0; j < 2; ++j) {             // A: rows wid*16 .. +15
      int rb = wid * 16 + j * 8;
      gload_lds16(q + (((size_t)(m0 + rb + r8)) << 10) + k0 + s8 * 8, &Ab[buf][rb * 64]);
    }
#pragma unroll
    for (int j = 0; j < 4; ++j) {             // B: rows wid*32 .. +31
      int rb = wid * 32 + j * 8;
      gload_lds16(Wcat + (((size_t)(rb + r8)) << 10) + k0 + s8 * 8, &Bb[buf][rb * 64]);
    }
  };

  stage(0, 0);
  for (int kt = 0; kt < 16; ++kt) {
    int cur = kt & 1;
    __syncthreads();
    if (kt < 15) stage(cur ^ 1, kt + 1);
#pragma unroll
    for (int s = 0; s < 2; ++s) {
      bf16x8v af[2], bfr[4];
#pragma unroll
      for (int r = 0; r < 2; ++r)
        af[r] = *(const bf16x8v*)&Ab[cur][(wrow * 32 + r * 16 + l15) * 64 + s * 32 + quad * 8];
#pragma unroll
      for (int c = 0; c < 4; ++c)
        bfr[c] = *(const bf16x8v*)&Bb[cur][(wcol * 64 + c * 16 + l15) * 64 + s * 32 + quad * 8];
#pragma unroll
      for (int r = 0; r < 2; ++r)
#pragma unroll
        for (int c = 0; c < 4; ++c)
          acc[r][c] = __builtin_amdgcn_mfma_f32_16x16x32_bf16(af[r], bfr[c], acc[r][c], 0, 0, 0);
    }
  }

#pragma unroll
  for (int c = 0; c < 4; ++c) {
    int col = wcol * 64 + c * 16 + l15;       // col<64 is wave-uniform (wcol)
    float bias = (col < 64) ? b_slope[col] : b_int[col - 64];
#pragma unroll
    for (int r = 0; r < 2; ++r)
#pragma unroll
      for (int e = 0; e < 4; ++e) {
        int row = m0 + wrow * 32 + r * 16 + quad * 4 + e;
        float v = acc[r][c][e] + bias;
        if (col < 64) {
          float xc = fminf(fmaxf(v, -15.f), 15.f);
          float t = __expf(2.f * xc);
          out[(size_t)row * 64 + col] = (t - 1.f) / (t + 1.f);   // tanh
        } else {
          out[(size_t)4194304 + (size_t)row * 64 + (col - 64)] = v;
        }
      }
  }
}

// ---------------- fallback prep (round-1, for small ws) --------------------------------
__global__ __launch_bounds__(256) void prep_kernel(const float* __restrict__ W1,
                                                   const float* __restrict__ Wslope,
                                                   const float* __restrict__ Wint,
                                                   __bf16* __restrict__ toep,
                                                   __bf16* __restrict__ Wcat) {
  int id = blockIdx.x * 256 + threadIdx.x;
  if (id < 1024 * 1024) {
    int i = id >> 10, j = id & 1023;
    int p = 1023 - i + j;
    float v = (p < 1024) ? W1[(size_t)(1023 - p) << 10] : W1[p - 1023];
    toep[id] = (__bf16)v;
  } else {
    int id2 = id - 1024 * 1024;
    int n = id2 >> 10, k = id2 & 1023;
    float v = (n < 64) ? Wslope[((size_t)n << 10) + k] : Wint[((size_t)(n - 64) << 10) + k];
    Wcat[id2] = (__bf16)v;
  }
}

extern "C" void kernel_launch(void* const* d_in, const int* in_sizes, int n_in,
                              void* d_out, int out_size, void* d_ws, size_t ws_size,
                              hipStream_t stream) {
  const float* x  = (const float*)d_in[0];
  const float* h  = (const float*)d_in[1];
  const float* W1 = (const float*)d_in[2];
  const float* b1 = (const float*)d_in[3];
  const float* Ws = (const float*)d_in[4];
  const float* bs = (const float*)d_in[5];
  const float* Wi = (const float*)d_in[6];
  const float* bi = (const float*)d_in[7];
  char* ws = (char*)d_ws;

  const size_t SZ_Q    = 134217728;   // q    bf16 [65536,1024]
  const size_t SZ_ACAT = 134217728;   // Acat bf16 [65536,1024]
  const size_t SZ_TOEP = 2097152;     // toep bf16 [1024,1024]
  const size_t SZ_WCAT = 262144;      // Wcat bf16 [128,1024]
  const size_t need = SZ_Q + SZ_ACAT + SZ_TOEP + SZ_WCAT + 8192;

  __bf16* q = (__bf16*)ws;
  if (ws_size >= need) {
    __bf16* Acat  = (__bf16*)(ws + SZ_Q);
    __bf16* toep  = (__bf16*)(ws + SZ_Q + SZ_ACAT);
    __bf16* Wcat  = (__bf16*)(ws + SZ_Q + SZ_ACAT + SZ_TOEP);
    float* params = (float*)(ws + SZ_Q + SZ_ACAT + SZ_TOEP + SZ_WCAT);
    hipLaunchKernelGGL(params_kernel, dim3(8),     dim3(256), 0, stream, W1, params);
    hipLaunchKernelGGL(pack_kernel,   dim3(33344), dim3(256), 0, stream,
                       x, h, params, Ws, Wi, Acat, toep, Wcat);
    hipLaunchKernelGGL(gemm1_dma,     dim3(4096),  dim3(256), 0, stream, Acat, toep, b1, q);
    hipLaunchKernelGGL(gemm2_dma,     dim3(1024),  dim3(256), 0, stream, q, Wcat, bs, bi,
                       (float*)d_out);
  } else {
    __bf16* toep = (__bf16*)(ws + SZ_Q);
    __bf16* Wcat = (__bf16*)(ws + SZ_Q + SZ_TOEP);
    hipLaunchKernelGGL(prep_kernel,   dim3(4608), dim3(256), 0, stream, W1, Ws, Wi, toep, Wcat);
    hipLaunchKernelGGL(gemm1_fused,   dim3(4096), dim3(256), 0, stream, x, h, toep, b1, q);
    hipLaunchKernelGGL(gemm2_dma,     dim3(1024), dim3(256), 0, stream, q, Wcat, bs, bi,
                       (float*)d_out);
  }
}

// Round 3
// 611.795 us; speedup vs baseline: 1.0781x; 1.0781x over previous
//
#include <hip/hip_runtime.h>
#include <cstdint>
#include <cstddef>

typedef __bf16 bf16x8v __attribute__((ext_vector_type(8)));
typedef float f32x4v __attribute__((ext_vector_type(4)));

// async global->LDS, 16B per lane; LDS dest is wave-uniform base (HW adds lane*16)
__device__ __forceinline__ void gload_lds16(const void* g, void* l) {
  __builtin_amdgcn_global_load_lds((const __attribute__((address_space(1))) void*)g,
                                   (__attribute__((address_space(3))) void*)l,
                                   16, 0, 0);
}

__device__ __forceinline__ bf16x8v cvt_bf16x8(f32x4v a, f32x4v b) {
  bf16x8v r;
  r[0] = (__bf16)a[0]; r[1] = (__bf16)a[1]; r[2] = (__bf16)a[2]; r[3] = (__bf16)a[3];
  r[4] = (__bf16)b[0]; r[5] = (__bf16)b[1]; r[6] = (__bf16)b[2]; r[7] = (__bf16)b[3];
  return r;
}

// ---------------- params: linearize the Toeplitz generator (2047 fp32) ----------------
__global__ __launch_bounds__(256) void params_kernel(const float* __restrict__ W1,
                                                     float* __restrict__ params) {
  int p = blockIdx.x * 256 + threadIdx.x;
  if (p < 2047)
    params[p] = (p < 1024) ? W1[(size_t)(1023 - p) << 10] : W1[p - 1023];
}

// ---------------- pack: Acat bf16 [65536,1024], toep bf16 [1024,1024], Wcat [128,1024]
__global__ __launch_bounds__(256) void pack_kernel(const float* __restrict__ x,
                                                   const float* __restrict__ h,
                                                   const float* __restrict__ params,
                                                   const float* __restrict__ Ws,
                                                   const float* __restrict__ Wi,
                                                   __bf16* __restrict__ Acat,
                                                   __bf16* __restrict__ toep,
                                                   __bf16* __restrict__ Wcat) {
  long u = (long)blockIdx.x * 256 + threadIdx.x;
  if (u < 8388608L) {                       // Acat: 65536*1024/8 units
    int r = (int)(u >> 7), cg = (int)(u & 127);
    const float* s = (cg < 8) ? x + (size_t)r * 64 + cg * 8
                              : h + (size_t)r * 960 + (cg - 8) * 8;
    f32x4v a = *(const f32x4v*)s, b = *(const f32x4v*)(s + 4);
    *(bf16x8v*)(Acat + ((size_t)r << 10) + cg * 8) = cvt_bf16x8(a, b);
  } else if (u < 8519680L) {                // toep: 1024*1024/8 units
    long t = u - 8388608L;
    int i = (int)(t >> 7), j0 = (int)(t & 127) * 8;
    const float* s = params + (1023 - i + j0);   // unaligned scalar loads, L2-hot
    bf16x8v o;
#pragma unroll
    for (int e = 0; e < 8; ++e) o[e] = (__bf16)s[e];
    *(bf16x8v*)(toep + ((size_t)i << 10) + j0) = o;
  } else {                                  // Wcat: 128*1024/8 units
    long t = u - 8519680L;
    int n = (int)(t >> 7), k0 = (int)(t & 127) * 8;
    const float* s = (n < 64) ? Ws + ((size_t)n << 10) + k0
                              : Wi + ((size_t)(n - 64) << 10) + k0;
    f32x4v a = *(const f32x4v*)s, b = *(const f32x4v*)(s + 4);
    *(bf16x8v*)(Wcat + ((size_t)n << 10) + k0) = cvt_bf16x8(a, b);
  }
}

// ---------------- GEMM1: q = relu(Acat @ toep^T + b1), bf16 out -----------------------
// 128x128 tile, BK=32, dbuf DMA, XCD-swizzled grid, unroll-2 K loop
__global__ __launch_bounds__(256) void gemm1_dma(const __bf16* __restrict__ Acat,
                                                 const __bf16* __restrict__ toep,
                                                 const float* __restrict__ b1,
                                                 __bf16* __restrict__ q) {
  __shared__ __align__(16) __bf16 Ab0[128 * 32], Ab1[128 * 32];
  __shared__ __align__(16) __bf16 Bb0[128 * 32], Bb1[128 * 32];
  const int tid = threadIdx.x, wid = tid >> 6, lane = tid & 63;
  const int wrow = wid >> 1, wcol = wid & 1;
  // XCD swizzle: consecutive bids round-robin over 8 XCDs. Give XCD x the m-tiles
  // {x, 8+x, ...}, each with its 8 n-tiles CONSECUTIVE in x's stream -> the 256 KB
  // A-tile and the 2 MB toep stay resident in that XCD's 4 MB L2.
  const int bid = blockIdx.x;
  const int xcd = bid & 7, j = bid >> 3;
  const int m0 = (((j >> 3) << 3) | xcd) << 7;   // m-tile 0..511
  const int n0 = (j & 7) << 7;                   // n-tile 0..7
  const int quad = lane >> 4, l15 = lane & 15;
  const int rl = lane >> 2, seg = lane & 3;      // DMA: 4 lanes/row, 16 rows/instr

  f32x4v acc[4][4] = {};

  // per-lane global pointers; advance +32 bf16 (64 B) per staged kt
  const __bf16* gA = Acat + (((size_t)(m0 + wid * 32 + rl)) << 10) + seg * 8;
  const __bf16* gB = toep + (((size_t)(n0 + wid * 32 + rl)) << 10) + seg * 8;
  const size_t ROW16 = (size_t)16 << 10;         // 16 rows stride (elements)

  auto stage = [&](__bf16* la, __bf16* lb) {
    int rb = wid * 32;
    gload_lds16(gA,         &la[rb * 32]);
    gload_lds16(gA + ROW16, &la[(rb + 16) * 32]);
    gload_lds16(gB,         &lb[rb * 32]);
    gload_lds16(gB + ROW16, &lb[(rb + 16) * 32]);
    gA += 32; gB += 32;
  };

  auto compute = [&](const __bf16* la, const __bf16* lb) {
    bf16x8v af[4], bfr[4];
#pragma unroll
    for (int r = 0; r < 4; ++r)
      af[r] = *(const bf16x8v*)&la[(wrow * 64 + r * 16 + l15) * 32 + quad * 8];
#pragma unroll
    for (int c = 0; c < 4; ++c)
      bfr[c] = *(const bf16x8v*)&lb[(wcol * 64 + c * 16 + l15) * 32 + quad * 8];
#pragma unroll
    for (int r = 0; r < 4; ++r)
#pragma unroll
      for (int c = 0; c < 4; ++c)
        acc[r][c] = __builtin_amdgcn_mfma_f32_16x16x32_bf16(af[r], bfr[c], acc[r][c], 0, 0, 0);
  };

  stage(Ab0, Bb0);                               // kt = 0
  for (int kt = 0; kt < 32; kt += 2) {
    __syncthreads();                             // drains DMA into buf0; guards buf1 reuse
    stage(Ab1, Bb1);                             // kt+1 (always <= 31)
    compute(Ab0, Bb0);
    __syncthreads();                             // drains DMA into buf1; guards buf0 reuse
    if (kt < 30) stage(Ab0, Bb0);                // kt+2
    compute(Ab1, Bb1);
  }

  // epilogue: C/D col=lane&15, row=quad*4+e
#pragma unroll
  for (int c = 0; c < 4; ++c) {
    int col = n0 + wcol * 64 + c * 16 + l15;
    float bias = b1[col];
#pragma unroll
    for (int r = 0; r < 4; ++r)
#pragma unroll
      for (int e = 0; e < 4; ++e) {
        int row = m0 + wrow * 64 + r * 16 + quad * 4 + e;
        q[((size_t)row << 10) + col] = (__bf16)fmaxf(acc[r][c][e] + bias, 0.0f);
      }
  }
}

// ---------------- GEMM2: [slope|intercept] = act(q @ Wcat^T + bias) -------------------
// 64-row tiles (1024 blocks), BK=64, dbuf DMA; wave tile 32x64
__global__ __launch_bounds__(256) void gemm2_dma(const __bf16* __restrict__ q,
                                                 const __bf16* __restrict__ Wcat,
                                                 const float* __restrict__ b_slope,
                                                 const float* __restrict__ b_int,
                                                 float* __restrict__ out) {
  __shared__ __align__(16) __bf16 Ab[2][64 * 64];
  __shared__ __align__(16) __bf16 Bb[2][128 * 64];
  const int tid = threadIdx.x, wid = tid >> 6, lane = tid & 63;
  const int wrow = wid >> 1, wcol = wid & 1;
  const int m0 = blockIdx.x << 6;
  const int quad = lane >> 4, l15 = lane & 15;
  const int r8 = lane >> 3, s8 = lane & 7;    // DMA: 8 lanes/row (128B rows), 8 rows/instr

  f32x4v acc[2][4] = {};

  auto stage = [&](int buf, int kt) {
    int k0 = kt << 6;
#pragma unroll
    for (int j = 0; j < 2; ++j) {
      int rb = wid * 16 + j * 8;
      gload_lds16(q + (((size_t)(m0 + rb + r8)) << 10) + k0 + s8 * 8, &Ab[buf][rb * 64]);
    }
#pragma unroll
    for (int j = 0; j < 4; ++j) {
      int rb = wid * 32 + j * 8;
      gload_lds16(Wcat + (((size_t)(rb + r8)) << 10) + k0 + s8 * 8, &Bb[buf][rb * 64]);
    }
  };

  stage(0, 0);
  for (int kt = 0; kt < 16; ++kt) {
    int cur = kt & 1;
    __syncthreads();
    if (kt < 15) stage(cur ^ 1, kt + 1);
#pragma unroll
    for (int s = 0; s < 2; ++s) {
      bf16x8v af[2], bfr[4];
#pragma unroll
      for (int r = 0; r < 2; ++r)
        af[r] = *(const bf16x8v*)&Ab[cur][(wrow * 32 + r * 16 + l15) * 64 + s * 32 + quad * 8];
#pragma unroll
      for (int c = 0; c < 4; ++c)
        bfr[c] = *(const bf16x8v*)&Bb[cur][(wcol * 64 + c * 16 + l15) * 64 + s * 32 + quad * 8];
#pragma unroll
      for (int r = 0; r < 2; ++r)
#pragma unroll
        for (int c = 0; c < 4; ++c)
          acc[r][c] = __builtin_amdgcn_mfma_f32_16x16x32_bf16(af[r], bfr[c], acc[r][c], 0, 0, 0);
    }
  }

#pragma unroll
  for (int c = 0; c < 4; ++c) {
    int col = wcol * 64 + c * 16 + l15;       // col<64 is wave-uniform (wcol)
    float bias = (col < 64) ? b_slope[col] : b_int[col - 64];
#pragma unroll
    for (int r = 0; r < 2; ++r)
#pragma unroll
      for (int e = 0; e < 4; ++e) {
        int row = m0 + wrow * 32 + r * 16 + quad * 4 + e;
        float v = acc[r][c][e] + bias;
        if (col < 64) {
          float xc = fminf(fmaxf(v, -15.f), 15.f);
          float t = __expf(2.f * xc);
          out[(size_t)row * 64 + col] = (t - 1.f) / (t + 1.f);   // tanh
        } else {
          out[(size_t)4194304 + (size_t)row * 64 + (col - 64)] = v;
        }
      }
  }
}

// ---------------- fallback (small ws): fused fp32-A gemm1 ------------------------------
__global__ __launch_bounds__(256) void gemm1_fused(const float* __restrict__ x,
                                                   const float* __restrict__ h,
                                                   const __bf16* __restrict__ toep,
                                                   const float* __restrict__ b1,
                                                   __bf16* __restrict__ q) {
  __shared__ __align__(16) __bf16 At[128 * 32];
  __shared__ __align__(16) __bf16 Bt[128 * 32];
  const int tid = threadIdx.x, wid = tid >> 6, lane = tid & 63;
  const int wrow = wid >> 1, wcol = wid & 1;
  const int m0 = (blockIdx.x >> 3) << 7;
  const int n0 = (blockIdx.x & 7) << 7;
  const int quad = lane >> 4, l15 = lane & 15;
  const int rl = lane >> 2, seg = lane & 3;

  f32x4v acc[4][4] = {};
  auto a_ptr = [&](int k0, int t) -> const f32x4v* {
    const float* s; int ld, kk;
    if (k0 < 64) { s = x; ld = 64; kk = k0; } else { s = h; ld = 960; kk = k0 - 64; }
    int row = m0 + wid * 32 + t * 16 + rl;
    return (const f32x4v*)(s + (size_t)row * ld + kk + seg * 8);
  };
  f32x4v pv[2][2];
  { const f32x4v* p0 = a_ptr(0, 0); pv[0][0] = p0[0]; pv[0][1] = p0[1];
    const f32x4v* p1 = a_ptr(0, 1); pv[1][0] = p1[0]; pv[1][1] = p1[1]; }

  for (int k0 = 0; k0 < 1024; k0 += 32) {
    __syncthreads();
    { int rb = wid * 32;
#pragma unroll
      for (int c = 0; c < 2; ++c) {
        int row = rb + c * 16 + rl;
        gload_lds16(toep + (((size_t)(n0 + row)) << 10) + k0 + seg * 8, &Bt[(rb + c * 16) * 32]);
      } }
#pragma unroll
    for (int t = 0; t < 2; ++t) {
      int row = wid * 32 + t * 16 + rl;
      *(bf16x8v*)&At[row * 32 + seg * 8] = cvt_bf16x8(pv[t][0], pv[t][1]);
    }
    __syncthreads();
    if (k0 + 32 < 1024) {
      const f32x4v* p0 = a_ptr(k0 + 32, 0); f32x4v n00 = p0[0], n01 = p0[1];
      const f32x4v* p1 = a_ptr(k0 + 32, 1); f32x4v n10 = p1[0], n11 = p1[1];
      pv[0][0] = n00; pv[0][1] = n01; pv[1][0] = n10; pv[1][1] = n11;
    }
    bf16x8v af[4], bfr[4];
#pragma unroll
    for (int r = 0; r < 4; ++r)
      af[r] = *(const bf16x8v*)&At[(wrow * 64 + r * 16 + l15) * 32 + quad * 8];
#pragma unroll
    for (int c = 0; c < 4; ++c)
      bfr[c] = *(const bf16x8v*)&Bt[(wcol * 64 + c * 16 + l15) * 32 + quad * 8];
#pragma unroll
    for (int r = 0; r < 4; ++r)
#pragma unroll
      for (int c = 0; c < 4; ++c)
        acc[r][c] = __builtin_amdgcn_mfma_f32_16x16x32_bf16(af[r], bfr[c], acc[r][c], 0, 0, 0);
  }
#pragma unroll
  for (int c = 0; c < 4; ++c) {
    int col = n0 + wcol * 64 + c * 16 + l15;
    float bias = b1[col];
#pragma unroll
    for (int r = 0; r < 4; ++r)
#pragma unroll
      for (int e = 0; e < 4; ++e) {
        int row = m0 + wrow * 64 + r * 16 + quad * 4 + e;
        q[((size_t)row << 10) + col] = (__bf16)fmaxf(acc[r][c][e] + bias, 0.0f);
      }
  }
}

__global__ __launch_bounds__(256) void prep_kernel(const float* __restrict__ W1,
                                                   const float* __restrict__ Wslope,
                                                   const float* __restrict__ Wint,
                                                   __bf16* __restrict__ toep,
                                                   __bf16* __restrict__ Wcat) {
  int id = blockIdx.x * 256 + threadIdx.x;
  if (id < 1024 * 1024) {
    int i = id >> 10, j = id & 1023;
    int p = 1023 - i + j;
    float v = (p < 1024) ? W1[(size_t)(1023 - p) << 10] : W1[p - 1023];
    toep[id] = (__bf16)v;
  } else {
    int id2 = id - 1024 * 1024;
    int n = id2 >> 10, k = id2 & 1023;
    float v = (n < 64) ? Wslope[((size_t)n << 10) + k] : Wint[((size_t)(n - 64) << 10) + k];
    Wcat[id2] = (__bf16)v;
  }
}

extern "C" void kernel_launch(void* const* d_in, const int* in_sizes, int n_in,
                              void* d_out, int out_size, void* d_ws, size_t ws_size,
                              hipStream_t stream) {
  const float* x  = (const float*)d_in[0];
  const float* h  = (const float*)d_in[1];
  const float* W1 = (const float*)d_in[2];
  const float* b1 = (const float*)d_in[3];
  const float* Ws = (const float*)d_in[4];
  const float* bs = (const float*)d_in[5];
  const float* Wi = (const float*)d_in[6];
  const float* bi = (const float*)d_in[7];
  char* ws = (char*)d_ws;

  const size_t SZ_Q    = 134217728;   // q    bf16 [65536,1024]
  const size_t SZ_ACAT = 134217728;   // Acat bf16 [65536,1024]
  const size_t SZ_TOEP = 2097152;     // toep bf16 [1024,1024]
  const size_t SZ_WCAT = 262144;      // Wcat bf16 [128,1024]
  const size_t need = SZ_Q + SZ_ACAT + SZ_TOEP + SZ_WCAT + 8192;

  __bf16* q = (__bf16*)ws;
  if (ws_size >= need) {
    __bf16* Acat  = (__bf16*)(ws + SZ_Q);
    __bf16* toep  = (__bf16*)(ws + SZ_Q + SZ_ACAT);
    __bf16* Wcat  = (__bf16*)(ws + SZ_Q + SZ_ACAT + SZ_TOEP);
    float* params = (float*)(ws + SZ_Q + SZ_ACAT + SZ_TOEP + SZ_WCAT);
    hipLaunchKernelGGL(params_kernel, dim3(8),     dim3(256), 0, stream, W1, params);
    hipLaunchKernelGGL(pack_kernel,   dim3(33344), dim3(256), 0, stream,
                       x, h, params, Ws, Wi, Acat, toep, Wcat);
    hipLaunchKernelGGL(gemm1_dma,     dim3(4096),  dim3(256), 0, stream, Acat, toep, b1, q);
    hipLaunchKernelGGL(gemm2_dma,     dim3(1024),  dim3(256), 0, stream, q, Wcat, bs, bi,
                       (float*)d_out);
  } else {
    __bf16* toep = (__bf16*)(ws + SZ_Q);
    __bf16* Wcat = (__bf16*)(ws + SZ_Q + SZ_TOEP);
    hipLaunchKernelGGL(prep_kernel,   dim3(4608), dim3(256), 0, stream, W1, Ws, Wi, toep, Wcat);
    hipLaunchKernelGGL(gemm1_fused,   dim3(4096), dim3(256), 0, stream, x, h, toep, b1, q);
    hipLaunchKernelGGL(gemm2_dma,     dim3(1024), dim3(256), 0, stream, q, Wcat, bs, bi,
                       (float*)d_out);
  }
}